// Round 1
// baseline (449.450 us; speedup 1.0000x reference)
//
#include <hip/hip_runtime.h>
#include <stdint.h>

typedef float f32x4 __attribute__((ext_vector_type(4)));

#define LDS_STRIDE 272   // 256 fp8 bytes per row + 16B pad (keeps b64 reads ~conflict-free)

// ---- fp8 e4m3fn (OCP) encode with RNE ----
#if __has_builtin(__builtin_amdgcn_cvt_pk_fp8_f32)
__device__ inline uint32_t pack_fp8x4(float a, float b, float c, float d) {
  int v = __builtin_amdgcn_cvt_pk_fp8_f32(a, b, 0, false);
  v = __builtin_amdgcn_cvt_pk_fp8_f32(c, d, v, true);
  return (uint32_t)v;
}
#else
// manual RNE encode for small integers |q| <= 127 (exact for our quantized values)
__device__ inline uint32_t fp8_one(float qf) {
  float af = fabsf(qf);
  int a = (int)af;
  uint32_t sign = (__builtin_bit_cast(uint32_t, qf) >> 24) & 0x80u;
  if (a == 0) return sign;
  int E = 31 - __builtin_clz((unsigned)a);
  int exp8 = E + 7, mant;
  if (E <= 3) {
    mant = (a << (3 - E)) & 7;
  } else {
    int shift = E - 3, step = 1 << shift, half = step >> 1;
    int m = a >> shift, rem = a & (step - 1);
    m += (rem > half || (rem == half && (m & 1)));
    if (m == 16) { m = 8; exp8 += 1; }
    mant = m & 7;
  }
  return sign | (uint32_t)((exp8 << 3) | mant);
}
__device__ inline uint32_t pack_fp8x4(float a, float b, float c, float d) {
  return fp8_one(a) | (fp8_one(b) << 8) | (fp8_one(c) << 16) | (fp8_one(d) << 24);
}
#endif

__device__ inline float qclamp(float t) {
  return fminf(fmaxf(rintf(t), -127.f), 127.f);
}

// ---- kernel 1: quantize weight [256][256] into fp8 qw + scales rs' = s/(127*127) ----
__global__ void qweight_kernel(const float* __restrict__ w,
                               uint8_t* __restrict__ qw,
                               float* __restrict__ rs) {
  const int ob = blockIdx.x >> 1, kb = blockIdx.x & 1;
  const int tid = threadIdx.x;
  __shared__ float red[256];
  float4 v[16];
  float mx = 0.f;
#pragma unroll
  for (int j = 0; j < 16; ++j) {
    int slot = j * 256 + tid;           // 4096 float4-slots in the 128x128 block
    int r = slot >> 5, c4 = slot & 31;
    v[j] = *(const float4*)(w + (ob * 128 + r) * 256 + kb * 128 + c4 * 4);
    mx = fmaxf(mx, fmaxf(fmaxf(fabsf(v[j].x), fabsf(v[j].y)),
                         fmaxf(fabsf(v[j].z), fabsf(v[j].w))));
  }
  red[tid] = mx;
  __syncthreads();
  for (int s = 128; s > 0; s >>= 1) {
    if (tid < s) red[tid] = fmaxf(red[tid], red[tid + s]);
    __syncthreads();
  }
  float s = red[0];
  s = (s == 0.f) ? 1.f : s;
  const float inv = 127.f / s;
#pragma unroll
  for (int j = 0; j < 16; ++j) {
    int slot = j * 256 + tid;
    int r = slot >> 5, c4 = slot & 31;
    uint32_t p = pack_fp8x4(qclamp(v[j].x * inv), qclamp(v[j].y * inv),
                            qclamp(v[j].z * inv), qclamp(v[j].w * inv));
    *(uint32_t*)(qw + (ob * 128 + r) * 256 + kb * 128 + c4 * 4) = p;
  }
  if (tid == 0) rs[ob * 2 + kb] = s * (1.f / 16129.f);  // s / 127^2
}

// ---- kernel 2: fused quantize-x + fp8 GEMM + scale + bf16-round + bias ----
__global__ __launch_bounds__(512, 4) void fused_kernel(
    const float* __restrict__ x, const uint8_t* __restrict__ qw,
    const float* __restrict__ rs, const float* __restrict__ bias,
    float* __restrict__ out) {
  __shared__ __align__(16) uint8_t At[128 * LDS_STRIDE];  // fp8 A-tile [128 rows][256 k]
  __shared__ float lsh[128][2];                            // per-(row, kblock) scale
  const int tid = threadIdx.x;
  const int lane = tid & 63, wid = tid >> 6;
  const long row0 = (long)blockIdx.x * 128;

  // ---- stage + quantize x tile: 256 row-blocks (row,kb), 4 threads each ----
  for (int it = 0; it < 2; ++it) {
    int rb = it * 128 + (tid >> 2);
    int row = rb >> 1, kb = rb & 1, sub = tid & 3;
    const float4* src = (const float4*)(x + (row0 + row) * 256 + kb * 128);
    float4 v[8];
#pragma unroll
    for (int j = 0; j < 8; ++j) v[j] = src[j * 4 + sub];  // interleaved: 64B/4-lane group
    float mx = 0.f;
#pragma unroll
    for (int j = 0; j < 8; ++j)
      mx = fmaxf(mx, fmaxf(fmaxf(fabsf(v[j].x), fabsf(v[j].y)),
                           fmaxf(fabsf(v[j].z), fabsf(v[j].w))));
    mx = fmaxf(mx, __shfl_xor(mx, 1));
    mx = fmaxf(mx, __shfl_xor(mx, 2));
    float s = (mx == 0.f) ? 1.f : mx;
    float inv = 127.f / s;
    uint32_t base = (uint32_t)row * LDS_STRIDE + kb * 128;
#pragma unroll
    for (int j = 0; j < 8; ++j) {
      uint32_t p = pack_fp8x4(qclamp(v[j].x * inv), qclamp(v[j].y * inv),
                              qclamp(v[j].z * inv), qclamp(v[j].w * inv));
      *(uint32_t*)(At + base + (uint32_t)(j * 4 + sub) * 4) = p;
    }
    if (sub == 0) lsh[row][kb] = s;
  }

  // ---- per-wave B cache: 32 output cols, full K=256, fp8, in registers ----
  const int col0 = wid * 32;
  const int colblk = col0 >> 7;
  long long bfrag[2][8];
#pragma unroll
  for (int ct = 0; ct < 2; ++ct)
#pragma unroll
    for (int st = 0; st < 8; ++st)
      bfrag[ct][st] = *(const long long*)(qw + (col0 + ct * 16 + (lane & 15)) * 256 +
                                          st * 32 + (lane >> 4) * 8);
  const float r0 = rs[colblk * 2 + 0];
  const float r1 = rs[colblk * 2 + 1];
  const float bias_v0 = bias[col0 + (lane & 15)];
  const float bias_v1 = bias[col0 + 16 + (lane & 15)];

  __syncthreads();

  // ---- 8 row-tiles of 16 rows; 2 col-tiles; K=256 = 2 blocks x 4 MFMA steps ----
  for (int r = 0; r < 8; ++r) {
    const uint32_t arow = (uint32_t)(r * 16 + (lane & 15)) * LDS_STRIDE + (lane >> 4) * 8;
    long long af[8];
#pragma unroll
    for (int st = 0; st < 8; ++st)
      af[st] = *(const long long*)(At + arow + st * 32);
    f32x4 acc[2][2] = {{{0.f,0.f,0.f,0.f},{0.f,0.f,0.f,0.f}},
                       {{0.f,0.f,0.f,0.f},{0.f,0.f,0.f,0.f}}};
#pragma unroll
    for (int st = 0; st < 8; ++st) {
      acc[0][st >> 2] = __builtin_amdgcn_mfma_f32_16x16x32_fp8_fp8(
          af[st], bfrag[0][st], acc[0][st >> 2], 0, 0, 0);
      acc[1][st >> 2] = __builtin_amdgcn_mfma_f32_16x16x32_fp8_fp8(
          af[st], bfrag[1][st], acc[1][st >> 2], 0, 0, 0);
    }
#pragma unroll
    for (int i = 0; i < 4; ++i) {
      int m = r * 16 + (lane >> 4) * 4 + i;
      float2 lsv = *(const float2*)(&lsh[m][0]);   // broadcast within 16-lane groups
      float s0 = lsv.x * r0, s1 = lsv.y * r1;
      {
        float val = acc[0][0][i] * s0 + acc[0][1][i] * s1;
        uint32_t u = __builtin_bit_cast(uint32_t, val);
        u = (u + 0x7fffu + ((u >> 16) & 1u)) & 0xffff0000u;  // bf16 RNE
        val = __builtin_bit_cast(float, u) + bias_v0;
        out[(row0 + m) * 256 + col0 + (lane & 15)] = val;
      }
      {
        float val = acc[1][0][i] * s0 + acc[1][1][i] * s1;
        uint32_t u = __builtin_bit_cast(uint32_t, val);
        u = (u + 0x7fffu + ((u >> 16) & 1u)) & 0xffff0000u;
        val = __builtin_bit_cast(float, u) + bias_v1;
        out[(row0 + m) * 256 + col0 + 16 + (lane & 15)] = val;
      }
    }
  }
}

extern "C" void kernel_launch(void* const* d_in, const int* in_sizes, int n_in,
                              void* d_out, int out_size, void* d_ws, size_t ws_size,
                              hipStream_t stream) {
  const float* x = (const float*)d_in[0];
  const float* w = (const float*)d_in[1];
  const float* bias = (const float*)d_in[2];
  float* out = (float*)d_out;
  uint8_t* qw = (uint8_t*)d_ws;                       // 65536 B fp8 weight
  float* rs = (float*)((uint8_t*)d_ws + 256 * 256);   // 4 floats: s/127^2 per (ob,kb)

  hipLaunchKernelGGL(qweight_kernel, dim3(4), dim3(256), 0, stream, w, qw, rs);

  const long M = (long)in_sizes[0] / 256;             // 262144
  hipLaunchKernelGGL(fused_kernel, dim3((uint32_t)(M / 128)), dim3(512), 0, stream,
                     x, qw, rs, bias, out);
}